// Round 16
// baseline (463.750 us; speedup 1.0000x reference)
//
#include <hip/hip_runtime.h>

typedef __bf16 bf16;
typedef __bf16 bf16x4 __attribute__((ext_vector_type(4)));
typedef __bf16 bf16x8 __attribute__((ext_vector_type(8)));
typedef float f32x4 __attribute__((ext_vector_type(4)));

#define DEVI __device__ __forceinline__

typedef const __attribute__((address_space(1))) void* gas1;
typedef __attribute__((address_space(3))) void* las3;

// ---------------------------------------------------------------------------
// XCD-chunked bijective block remap (T1, m204 form).
// ---------------------------------------------------------------------------
DEVI int xcd_chunk(int bid, int nwg)
{
  const int q = nwg >> 3, r = nwg & 7;
  const int xcd = bid & 7, rank = bid >> 3;
  return (xcd < r) ? xcd * (q + 1) + rank
                   : r * (q + 1) + (xcd - r) * q + rank;
}

// ---------------------------------------------------------------------------
// Stage a [rows x 64] bf16 tile (row bytes = 128) into LDS via global_load_lds,
// with st-style XOR swizzle (linear LDS dest + pre-swizzled global source).
// ---------------------------------------------------------------------------
DEVI void stage_tile(const bf16* g, int ld, char* lds, int bytes, int tid)
{
  const int wv = tid >> 6, lane = tid & 63;
  const char* gb = (const char*)g;
  const long rowb = (long)ld * 2;
  for (int off = wv * 1024; off < bytes; off += 4096) {
    const int o  = off + lane * 16;                 // linear LDS dest
    const int s  = o ^ (((o >> 7) & 7) << 4);       // pre-swizzled source pos
    const int r  = s >> 7;                          // 128B per tile row
    const int cb = s & 127;
    __builtin_amdgcn_global_load_lds((gas1)(gb + (long)r * rowb + cb),
                                     (las3)(lds + off), 16, 0, 0);
  }
}

template<int N> DEVI void waitvm()
{
  if constexpr (N == 8)      asm volatile("s_waitcnt vmcnt(8)" ::: "memory");
  else if constexpr (N == 6) asm volatile("s_waitcnt vmcnt(6)" ::: "memory");
  else if constexpr (N == 4) asm volatile("s_waitcnt vmcnt(4)" ::: "memory");
  else if constexpr (N == 2) asm volatile("s_waitcnt vmcnt(2)" ::: "memory");
  else                       asm volatile("s_waitcnt vmcnt(0)" ::: "memory");
}

// Wave-local LDS fence: orders ds ops across lanes of ONE wave.
DEVI void wave_lds_fence()
{
  asm volatile("s_waitcnt lgkmcnt(0)" ::: "memory");
  __builtin_amdgcn_sched_barrier(0);
}

// ---------------------------------------------------------------------------
// Epilogue functors
// ---------------------------------------------------------------------------
struct EpiProj {
  const float* bias; const float* x; float* src;
  DEVI void operator()(int z, int row, int col, float v) const {
    const long i = (long)row * 768 + col;
    src[i] = v + bias[col] + x[i];
  }
};

struct EpiGelu {
  const float* bias; bf16* g;
  DEVI void operator()(int z, int row, int col, float v) const {
    const float t = v + bias[col];
    const float r = 0.5f * t * (1.0f + erff(t * 0.70710678118654752f));
    g[(long)row * 3072 + col] = (bf16)r;
  }
};

struct EpiOut {
  const float* bias; const float* lnf; float* outp;
  DEVI void operator()(int z, int row, int col, float v) const {
    const long i = (long)row * 768 + col;
    outp[i] = v + bias[col] + lnf[i];   // final residual uses POST-LN1 src
  }
};

// ---------------------------------------------------------------------------
// bf16 GEMM, 2-phase double-buffered, counted vmcnt; XCD-chunked.
// 128x64 tiles, 4 waves (2x2), FM=4 FN=2. LDS 48KB -> 3 blocks/CU.
// ---------------------------------------------------------------------------
template<int BM, int BN, int WC, int FM, int FN, int WPE, class Epi>
__global__ __launch_bounds__(256, WPE) void gemm_k(
    const bf16* __restrict__ A, long abatch,
    const bf16* __restrict__ B, long bbatch,
    int lda, int ldb, int K, Epi epi)
{
  constexpr int BK = 64;
  constexpr int AB = BM * BK * 2, BB = BN * BK * 2;
  constexpr int BUFB = AB + BB;
  constexpr int LPS = BUFB / 4096;          // global_load_lds per wave per stage
  __shared__ char smem[2 * BUFB];

  const int tid = threadIdx.x, lane = tid & 63, wv = tid >> 6;
  const int wr = wv / WC, wc = wv % WC;
  const int NT = gridDim.x;
  const int nwg = NT * gridDim.y;
  const int wid = xcd_chunk(blockIdx.y * NT + blockIdx.x, nwg);
  const int mt = wid / NT, nt = wid % NT;
  const int z = blockIdx.z;
  const long abase = (long)z * abatch + (long)mt * BM * lda;
  const long bbase = (long)z * bbatch + (long)nt * BN * ldb;
  const int l15 = lane & 15;
  const int sw = (lane & 7) << 4;           // per-lane read swizzle

  auto stage_all = [&](int buf, int kt) {
    char* base = smem + buf * BUFB;
    stage_tile(A + abase + kt, lda, base, AB, tid);
    stage_tile(B + bbase + kt, ldb, base + AB, BB, tid);
  };

  f32x4 acc[FM][FN];
#pragma unroll
  for (int m = 0; m < FM; ++m)
#pragma unroll
    for (int n = 0; n < FN; ++n) acc[m][n] = f32x4{0.f, 0.f, 0.f, 0.f};

  const int arow = wr * FM * 16, bcol = wc * FN * 16;
  const int T = K / BK;

  stage_all(0, 0);
  int cur = 0;
  for (int t = 0; t < T; ++t) {
    if (t + 1 < T) { stage_all(cur ^ 1, (t + 1) * BK); waitvm<LPS>(); }
    else           { waitvm<0>(); }
    __builtin_amdgcn_s_barrier();
    asm volatile("" ::: "memory");

    const char* As = smem + cur * BUFB;
    const char* Bs = As + AB;
#pragma unroll
    for (int ks = 0; ks < 2; ++ks) {
      const int ko = (ks * 64 + (lane >> 4) * 16) ^ sw;
      bf16x8 av[FM], bv[FN];
#pragma unroll
      for (int m = 0; m < FM; ++m)
        av[m] = *(const bf16x8*)(As + (arow + m * 16 + l15) * 128 + ko);
#pragma unroll
      for (int n = 0; n < FN; ++n)
        bv[n] = *(const bf16x8*)(Bs + (bcol + n * 16 + l15) * 128 + ko);
#pragma unroll
      for (int m = 0; m < FM; ++m)
#pragma unroll
        for (int n = 0; n < FN; ++n)
          acc[m][n] = __builtin_amdgcn_mfma_f32_16x16x32_bf16(av[m], bv[n], acc[m][n], 0, 0, 0);
    }
    asm volatile("s_waitcnt lgkmcnt(0)" ::: "memory");   // LDS reads done
    __builtin_amdgcn_s_barrier();                         // before buf reuse
    asm volatile("" ::: "memory");
    cur ^= 1;
  }

#pragma unroll
  for (int m = 0; m < FM; ++m)
#pragma unroll
    for (int n = 0; n < FN; ++n)
#pragma unroll
      for (int r = 0; r < 4; ++r) {
        const int grow = mt * BM + arow + m * 16 + (lane >> 4) * 4 + r;
        const int gcol = nt * BN + bcol + n * 16 + l15;
        epi(z, grow, gcol, acc[m][n][r]);
      }
}

// ---------------------------------------------------------------------------
// QKV GEMM with FUSED qkv_post epilogue + FUSED Gram stats (R15 known-good).
// ---------------------------------------------------------------------------
__global__ __launch_bounds__(256, 3) void gemm_qkv(
    const bf16* __restrict__ A, const bf16* __restrict__ B,
    const float* __restrict__ bias, bf16* __restrict__ q2h,
    bf16* __restrict__ k2h, bf16* __restrict__ vth,
    float* __restrict__ Gq, float* __restrict__ Gk,
    float* __restrict__ Sq, float* __restrict__ Sk)
{
  constexpr int BM = 128, BN = 64, BK = 64;
  constexpr int AB = BM * BK * 2, BB = BN * BK * 2;
  constexpr int BUFB = AB + BB;
  constexpr int LPS = BUFB / 4096;
  __shared__ char smem[2 * BUFB];
  __shared__ float rowsum[2][BM];

  const int tid = threadIdx.x, lane = tid & 63, wv = tid >> 6;
  const int wr = wv >> 1, wc = wv & 1;
  const int NT = 36;
  const int wid = xcd_chunk(blockIdx.y * NT + blockIdx.x, NT * 32);
  const int mt = wid / NT, nt = wid % NT;
  const int sec = nt / 12, h = nt - sec * 12;
  const long abase = (long)mt * BM * 768;
  const long bbase = (long)nt * BN * 768;
  const int l15 = lane & 15, lhi = lane >> 4;
  const int sw = (lane & 7) << 4;

  auto stage_all = [&](int buf, int kt) {
    char* base = smem + buf * BUFB;
    stage_tile(A + abase + kt, 768, base, AB, tid);
    stage_tile(B + bbase + kt, 768, base + AB, BB, tid);
  };

  f32x4 acc[4][2];
#pragma unroll
  for (int m = 0; m < 4; ++m)
#pragma unroll
    for (int n = 0; n < 2; ++n) acc[m][n] = f32x4{0.f, 0.f, 0.f, 0.f};

  const int arow = wr * 64, bcol = wc * 32;

  stage_all(0, 0);
  int cur = 0;
  for (int t = 0; t < 12; ++t) {
    if (t + 1 < 12) { stage_all(cur ^ 1, (t + 1) * BK); waitvm<LPS>(); }
    else            { waitvm<0>(); }
    __builtin_amdgcn_s_barrier();
    asm volatile("" ::: "memory");

    const char* As = smem + cur * BUFB;
    const char* Bs = As + AB;
#pragma unroll
    for (int ks = 0; ks < 2; ++ks) {
      const int ko = (ks * 64 + lhi * 16) ^ sw;
      bf16x8 av[4], bv[2];
#pragma unroll
      for (int m = 0; m < 4; ++m)
        av[m] = *(const bf16x8*)(As + (arow + m * 16 + l15) * 128 + ko);
#pragma unroll
      for (int n = 0; n < 2; ++n)
        bv[n] = *(const bf16x8*)(Bs + (bcol + n * 16 + l15) * 128 + ko);
#pragma unroll
      for (int m = 0; m < 4; ++m)
#pragma unroll
        for (int n = 0; n < 2; ++n)
          acc[m][n] = __builtin_amdgcn_mfma_f32_16x16x32_bf16(av[m], bv[n], acc[m][n], 0, 0, 0);
    }
    asm volatile("s_waitcnt lgkmcnt(0)" ::: "memory");
    __builtin_amdgcn_s_barrier();
    asm volatile("" ::: "memory");
    cur ^= 1;
  }

  // ---- fused epilogue ----
  float val[4][2][4];
#pragma unroll
  for (int m = 0; m < 4; ++m)
#pragma unroll
    for (int n = 0; n < 2; ++n)
#pragma unroll
      for (int r = 0; r < 4; ++r)
        val[m][n][r] = acc[m][n][r] + bias[nt * 64 + bcol + n * 16 + l15];

  if (sec < 2) {
#pragma unroll
    for (int m = 0; m < 4; ++m)
#pragma unroll
      for (int r = 0; r < 4; ++r) {
        float p = val[m][0][r] * val[m][0][r] + val[m][1][r] * val[m][1][r];
        p += __shfl_xor(p, 1);
        p += __shfl_xor(p, 2);
        p += __shfl_xor(p, 4);
        p += __shfl_xor(p, 8);
        if (l15 == 0) rowsum[wc][arow + m * 16 + lhi * 4 + r] = p;
      }
    __syncthreads();

    bf16* dst = (sec == 0) ? q2h : k2h;
    float* G  = (sec == 0) ? Gq  : Gk;
    float* S  = (sec == 0) ? Sq  : Sk;
    const int bq = mt >> 3;
    const int z = bq * 12 + h;
    char* T0 = smem;            // [64 d][128B] swizzled, rows n' 0..63
    char* T1 = smem + 8192;     //                       rows n' 64..127
    float colsum[2] = {0.f, 0.f};
#pragma unroll
    for (int m = 0; m < 4; ++m)
#pragma unroll
      for (int r = 0; r < 4; ++r) {
        const int row = arow + m * 16 + lhi * 4 + r;     // 0..127
        const float inv = 1.0f / (rowsum[0][row] + rowsum[1][row]);
        const int grow = mt * BM + row;
        const int nn = grow & 1023;
        const long base = (((long)z) * 1024 + nn) * 64;
        char* Tt = (row & 64) ? T1 : T0;
        const int np = row & 63;
#pragma unroll
        for (int n = 0; n < 2; ++n) {
          const float v = val[m][n][r];
          const int d = bcol + n * 16 + l15;
          const bf16 q2b = (bf16)(v * v * inv);
          dst[base + d] = q2b;
          *(bf16*)(Tt + d * 128 + ((np * 2) ^ ((d & 7) << 4))) = q2b;
          colsum[n] += (float)q2b;
        }
      }
    // Sq/Sk: reduce over lhi (this wave's 64 rows), cross-wr via atomics.
#pragma unroll
    for (int n = 0; n < 2; ++n) {
      float s = colsum[n];
      s += __shfl_xor(s, 16);
      s += __shfl_xor(s, 32);
      if (lane < 16) atomicAdd(&S[z * 64 + bcol + n * 16 + l15], s);
    }
    __syncthreads();   // T fully written (all waves) before Gram reads

    // Gram: G[d][e] += sum_n q2[n][d]*q2[n][e]; wave wv owns 4 of 16 tiles.
#pragma unroll
    for (int gi = 0; gi < 4; ++gi) {
      const int g = wv * 4 + gi;
      const int dr = g >> 2, ec = g & 3;
      f32x4 ga = f32x4{0.f, 0.f, 0.f, 0.f};
#pragma unroll
      for (int ks = 0; ks < 4; ++ks) {
        const char* Tt = (ks & 2) ? T1 : T0;
        const int ko = ((ks & 1) * 64 + lhi * 16) ^ sw;
        const bf16x8 av = *(const bf16x8*)(Tt + (dr * 16 + l15) * 128 + ko);
        const bf16x8 bv = *(const bf16x8*)(Tt + (ec * 16 + l15) * 128 + ko);
        ga = __builtin_amdgcn_mfma_f32_16x16x32_bf16(av, bv, ga, 0, 0, 0);
      }
#pragma unroll
      for (int r = 0; r < 4; ++r)
        atomicAdd(&G[(long)z * 4096 + (dr * 16 + lhi * 4 + r) * 64 + ec * 16 + l15],
                  ga[r]);
    }
  } else {
    // v-section: transpose the 128(n) x 64(d) tile through LDS, then
    // coalesced bf16x8 stores to vth[(b*12+h)*64 + d][nn0 + c].
    bf16* T = (bf16*)smem;             // [64 d][pitch 144] (post-loop reuse)
#pragma unroll
    for (int m = 0; m < 4; ++m)
#pragma unroll
      for (int n = 0; n < 2; ++n)
#pragma unroll
        for (int r = 0; r < 4; ++r) {
          const int row = arow + m * 16 + lhi * 4 + r;   // 0..127 (n)
          const int col = bcol + n * 16 + l15;           // 0..63  (d)
          T[col * 144 + row] = (bf16)val[m][n][r];
        }
    __syncthreads();
    const int bq = mt >> 3, nn0 = (mt & 7) * 128;
    const long basez = ((long)(bq * 12 + h) * 64) * 1024;
#pragma unroll
    for (int it = 0; it < 4; ++it) {
      const int flat = it * 2048 + tid * 8;
      const int d = flat >> 7, c = flat & 127;
      const bf16x8 o = *(const bf16x8*)&T[d * 144 + c];
      *(bf16x8*)&vth[basez + (long)d * 1024 + nn0 + c] = o;
    }
  }
}

// ---------------------------------------------------------------------------
// Fused attention tail — Q-IN-REGISTERS form: Q staged once into the Pall
// scratch (each wave's Q rows land exactly in its own wave-private window),
// fragments read to 8 VGPRs after the prologue barrier, then the LDS slot is
// reused as P scratch. LDS 40KB -> 4 blocks/CU (16 waves, +33% occupancy).
// Counted vmcnt(4) store drain + one-iter-ahead wn/bn prefetch (R14/R15).
// MFMA inputs bit-identical to R15.
// ---------------------------------------------------------------------------
__global__ __launch_bounds__(256, 4) void attn_fused(
    const bf16* __restrict__ q2h, const bf16* __restrict__ k2h,
    const bf16* __restrict__ vth, const float* __restrict__ stats,
    const float* __restrict__ wn, const float* __restrict__ bn,
    float* __restrict__ attn_out, bf16* __restrict__ oh)
{
  __shared__ char smem[40960];
  char* Ks0 = smem;
  char* Ks1 = smem + 8192;
  char* Vs0 = smem + 16384;
  char* Vs1 = smem + 24576;
  char* Pall = smem + 32768;           //  8KB: 4 waves x [16][64] bf16 (swz)

  const int tid = threadIdx.x, lane = tid & 63, wv = tid >> 6;
  const int wid = xcd_chunk(blockIdx.x, 768);
  const int b = wid & 3;               // fastest: wn/bn strip sharing
  const int mt = (wid >> 2) & 15;
  const int h = wid >> 6;
  const int zq = b * 12 + h;
  const float mu = stats[2 * b], rs = stats[2 * b + 1];
  const int l15 = lane & 15, lhi = lane >> 4;
  const int sw = (lane & 7) << 4;
  char* Ps = Pall + wv * 2048;         // wave-private [16 rows][128B]

  const long zoff = (long)zq * 65536;

  auto load_wb = [&](int nt, f32x4* wreg, f32x4* breg) {
#pragma unroll
    for (int rr = 0; rr < 4; ++rr) {
      const long grow = (long)mt * 64 + wv * 16 + rr * 4 + lhi;
      const long gcol = (long)nt * 64 + l15 * 4;
      wreg[rr] = *(const f32x4*)&wn[((long)h * 1024 + grow) * 1024 + gcol];
      breg[rr] = *(const f32x4*)&bn[((long)h * 1024 + grow) * 1024 + gcol];
    }
  };

  f32x4 wcur[4], bcur[4];
  load_wb(0, wcur, bcur);
  stage_tile(q2h + zoff + (long)mt * 4096, 64, Pall, 8192, tid);  // Q -> Pall
  stage_tile(k2h + zoff, 64, Ks0, 8192, tid);
  stage_tile(vth + zoff, 1024, Vs0, 8192, tid);
  __syncthreads();                      // DMA complete

  // Q fragments to registers (each wave reads ONLY its own Pall window).
  bf16x8 qa[2];
#pragma unroll
  for (int ks = 0; ks < 2; ++ks) {
    const int ko = (ks * 64 + lhi * 16) ^ sw;
    qa[ks] = *(const bf16x8*)(Pall + (wv * 16 + l15) * 128 + ko);
  }
  wave_lds_fence();                     // Q reads done before Ps overwrite

  f32x4 oacc[4];
#pragma unroll
  for (int n = 0; n < 4; ++n) oacc[n] = f32x4{0.f, 0.f, 0.f, 0.f};

  for (int nt = 0; nt < 16; ++nt) {
    const int cur = nt & 1;
    char* Kc = cur ? Ks1 : Ks0;
    char* Vc = cur ? Vs1 : Vs0;
    char* Kn = cur ? Ks0 : Ks1;
    char* Vn = cur ? Vs0 : Vs1;

    // next-iter prefetch: wn/bn to regs, then K/V DMA (counted at iter end).
    f32x4 wnx[4], bnx[4];
    if (nt + 1 < 16) {
      load_wb(nt + 1, wnx, bnx);
      stage_tile(k2h + zoff + (long)(nt + 1) * 4096, 64, Kn, 8192, tid);
      stage_tile(vth + zoff + (nt + 1) * 64, 1024, Vn, 8192, tid);
    }

    // ---- QK^T: av from regs, bv from staged K ----
    f32x4 acc[4];
#pragma unroll
    for (int n = 0; n < 4; ++n) acc[n] = f32x4{0.f, 0.f, 0.f, 0.f};
    __builtin_amdgcn_s_setprio(1);
#pragma unroll
    for (int ks = 0; ks < 2; ++ks) {
      const int ko = (ks * 64 + lhi * 16) ^ sw;
#pragma unroll
      for (int n = 0; n < 4; ++n) {
        const bf16x8 bv = *(const bf16x8*)(Kc + (n * 16 + l15) * 128 + ko);
        acc[n] = __builtin_amdgcn_mfma_f32_16x16x32_bf16(qa[ks], bv, acc[n], 0, 0, 0);
      }
    }
    __builtin_amdgcn_s_setprio(0);
    // s_ln = (s-mu)*rs -> bf16, into wave-private Ps (swizzled).
#pragma unroll
    for (int n = 0; n < 4; ++n)
#pragma unroll
      for (int r = 0; r < 4; ++r) {
        const int row = lhi * 4 + r;                 // local row 0..15
        const int cb = (n * 32 + l15 * 2) ^ ((row & 7) << 4);
        *(bf16*)(Ps + row * 128 + cb) = (bf16)((acc[n][r] - mu) * rs);
      }
    wave_lds_fence();  // cross-lane RAW within wave: QK^T writes -> LN reads

    // ---- LN: r = s_ln*w + b -> attn_out f32x4 (coalesced) + Ps in-place ----
#pragma unroll
    for (int rr = 0; rr < 4; ++rr) {
      const int row = rr * 4 + lhi;                  // local row 0..15
      const int cb = (l15 * 8) ^ ((row & 7) << 4);
      const bf16x4 s4 = *(const bf16x4*)(Ps + row * 128 + cb);
      const long grow = (long)mt * 64 + wv * 16 + row;
      const long gcol = (long)nt * 64 + l15 * 4;
      f32x4 r4;
      bf16x4 h4;
#pragma unroll
      for (int e = 0; e < 4; ++e) {
        const float r = (float)s4[e] * wcur[rr][e] + bcur[rr][e];
        r4[e] = r;
        h4[e] = (bf16)r;
      }
      *(f32x4*)&attn_out[((long)zq * 1024 + grow) * 1024 + gcol] = r4;
      *(bf16x4*)(Ps + row * 128 + cb) = h4;
    }
    wave_lds_fence();  // cross-lane RAW within wave: LN write-back -> PV reads

    // ---- PV: o[row, d] += sum_j P[row,j] vT[d,j] ----
    __builtin_amdgcn_s_setprio(1);
#pragma unroll
    for (int ks = 0; ks < 2; ++ks) {
      const int ko = (ks * 64 + lhi * 16) ^ sw;
      const bf16x8 av = *(const bf16x8*)(Ps + l15 * 128 + ko);
#pragma unroll
      for (int n = 0; n < 4; ++n) {
        const bf16x8 bv = *(const bf16x8*)(Vc + (n * 16 + l15) * 128 + ko);
        oacc[n] = __builtin_amdgcn_mfma_f32_16x16x32_bf16(av, bv, oacc[n], 0, 0, 0);
      }
    }
    __builtin_amdgcn_s_setprio(0);
    // counted drain: the 4 newest VMEM ops (attn stores) may stay in flight;
    // everything older (K/V DMA + wb loads) is forced complete.
    waitvm<4>();
    __builtin_amdgcn_s_barrier();
    asm volatile("" ::: "memory");

    if (nt + 1 < 16) {
#pragma unroll
      for (int rr = 0; rr < 4; ++rr) { wcur[rr] = wnx[rr]; bcur[rr] = bnx[rr]; }
    }
  }

  // ---- epilogue: o -> (B,N,C) bf16 ----
#pragma unroll
  for (int n = 0; n < 4; ++n)
#pragma unroll
    for (int r = 0; r < 4; ++r) {
      const int row = mt * 64 + wv * 16 + lhi * 4 + r;
      const int col = n * 16 + l15;
      oh[((long)(b * 1024 + row)) * 768 + h * 64 + col] = (bf16)oacc[n][r];
    }
}

// ---------------------------------------------------------------------------
// prep: all four weight casts + LN0 in ONE launch (block-range split).
// ---------------------------------------------------------------------------
__global__ __launch_bounds__(256) void prep(
    const float* __restrict__ qkvw, const float* __restrict__ projw,
    const float* __restrict__ fc1w, const float* __restrict__ fc2w,
    bf16* __restrict__ dq, bf16* __restrict__ dp,
    bf16* __restrict__ d1, bf16* __restrict__ d2,
    const float* __restrict__ x, const float* __restrict__ w,
    const float* __restrict__ bb, bf16* __restrict__ outh)
{
  __shared__ float red[256];
  const int bid = blockIdx.x, tid = threadIdx.x;
  if (bid < 6912) {
    const int i = bid * 256 + tid;     // n4 index over 1769472
    const float* s; bf16* d; int off;
    if (i < 442368)       { s = qkvw; d = dq; off = i; }
    else if (i < 589824)  { s = projw; d = dp; off = i - 442368; }
    else if (i < 1179648) { s = fc1w; d = d1; off = i - 589824; }
    else                  { s = fc2w; d = d2; off = i - 1179648; }
    const f32x4 v = *(const f32x4*)&s[(long)off * 4];
    bf16x4 o;
#pragma unroll
    for (int j = 0; j < 4; ++j) o[j] = (bf16)v[j];
    *(bf16x4*)&d[(long)off * 4] = o;
  } else {
    const int row = bid - 6912;
    const float* p = x + (long)row * 768;
    const float v0 = p[tid], v1 = p[tid + 256], v2 = p[tid + 512];
    red[tid] = v0 + v1 + v2;
    __syncthreads();
    for (int st = 128; st > 0; st >>= 1) { if (tid < st) red[tid] += red[tid + st]; __syncthreads(); }
    const float mu = red[0] * (1.0f / 768.0f);
    __syncthreads();
    const float d0 = v0 - mu, d1v = v1 - mu, d2v = v2 - mu;
    red[tid] = d0 * d0 + d1v * d1v + d2v * d2v;
    __syncthreads();
    for (int st = 128; st > 0; st >>= 1) { if (tid < st) red[tid] += red[tid + st]; __syncthreads(); }
    const float rs = rsqrtf(red[0] * (1.0f / 768.0f) + 1e-5f);
    const float dv[3] = {d0, d1v, d2v};
#pragma unroll
    for (int k = 0; k < 3; ++k) {
      const int c = tid + k * 256;
      outh[(long)row * 768 + c] = (bf16)(dv[k] * rs * w[c] + bb[c]);
    }
  }
}

// LayerNorm over rows of 768; writes bf16 (+ optional f32). (LN1)
__global__ __launch_bounds__(256) void ln_row(
    const float* __restrict__ in, const float* __restrict__ w,
    const float* __restrict__ b, bf16* __restrict__ outh,
    float* __restrict__ outf)
{
  __shared__ float red[256];
  const int row = blockIdx.x, tid = threadIdx.x;
  const float* p = in + (long)row * 768;
  const float v0 = p[tid], v1 = p[tid + 256], v2 = p[tid + 512];
  red[tid] = v0 + v1 + v2;
  __syncthreads();
  for (int st = 128; st > 0; st >>= 1) { if (tid < st) red[tid] += red[tid + st]; __syncthreads(); }
  const float mu = red[0] * (1.0f / 768.0f);
  __syncthreads();
  const float d0 = v0 - mu, d1 = v1 - mu, d2 = v2 - mu;
  red[tid] = d0 * d0 + d1 * d1 + d2 * d2;
  __syncthreads();
  for (int st = 128; st > 0; st >>= 1) { if (tid < st) red[tid] += red[tid + st]; __syncthreads(); }
  const float rs = rsqrtf(red[0] * (1.0f / 768.0f) + 1e-5f);
  const float dv[3] = {d0, d1, d2};
#pragma unroll
  for (int k = 0; k < 3; ++k) {
    const int c = tid + k * 256;
    const float h = dv[k] * rs * w[c] + b[c];
    outh[(long)row * 768 + c] = (bf16)h;
    if (outf) outf[(long)row * 768 + c] = h;
  }
}

// Per-batch mean / rstd of the attn tensor from Gram partials.
__global__ __launch_bounds__(256) void stats_final(
    const float* __restrict__ Gq, const float* __restrict__ Gk,
    const float* __restrict__ Sq, const float* __restrict__ Sk,
    float* __restrict__ stats)
{
  __shared__ double red[256];
  const int b = blockIdx.x, tid = threadIdx.x;
  double s2 = 0.0, s1 = 0.0;
  for (int h = 0; h < 12; ++h) {
    const float* gq = Gq + ((long)(b * 12 + h)) * 4096;
    const float* gk = Gk + ((long)(b * 12 + h)) * 4096;
    for (int i = tid; i < 4096; i += 256) s2 += (double)gq[i] * (double)gk[i];
    const float* sqp = Sq + (b * 12 + h) * 64;
    const float* skp = Sk + (b * 12 + h) * 64;
    for (int i = tid; i < 64; i += 256) s1 += (double)sqp[i] * (double)skp[i];
  }
  red[tid] = s2; __syncthreads();
  for (int st = 128; st > 0; st >>= 1) { if (tid < st) red[tid] += red[tid + st]; __syncthreads(); }
  const double S2 = red[0]; __syncthreads();
  red[tid] = s1; __syncthreads();
  for (int st = 128; st > 0; st >>= 1) { if (tid < st) red[tid] += red[tid + st]; __syncthreads(); }
  if (tid == 0) {
    const double S1 = red[0];
    const double cnt = 12.0 * 1024.0 * 1024.0;
    const double mean = S1 / cnt;
    const double var = S2 / cnt - mean * mean;
    stats[2 * b] = (float)mean;
    stats[2 * b + 1] = (float)(1.0 / sqrt(var + 1e-5));
  }
}

// ---------------------------------------------------------------------------
extern "C" void kernel_launch(void* const* d_in, const int* in_sizes, int n_in,
                              void* d_out, int out_size, void* d_ws, size_t ws_size,
                              hipStream_t stream)
{
  const float* x      = (const float*)d_in[0];
  const float* ln0_w  = (const float*)d_in[1];
  const float* ln0_b  = (const float*)d_in[2];
  const float* qkv_w  = (const float*)d_in[3];
  const float* qkv_b  = (const float*)d_in[4];
  const float* proj_w = (const float*)d_in[5];
  const float* proj_b = (const float*)d_in[6];
  const float* attn_w = (const float*)d_in[7];
  const float* attn_b = (const float*)d_in[8];
  const float* ln1_w  = (const float*)d_in[9];
  const float* ln1_b  = (const float*)d_in[10];
  const float* fc1_w  = (const float*)d_in[11];
  const float* fc1_b  = (const float*)d_in[12];
  const float* fc2_w  = (const float*)d_in[13];
  const float* fc2_b  = (const float*)d_in[14];

  float* out_src  = (float*)d_out;
  float* out_attn = out_src + 4L * 1024 * 768;       // 3145728

  char* p = (char*)d_ws;
  auto take = [&](long bytes) -> char* {
    char* r = p;
    p += (bytes + 255) & ~255L;
    return r;
  };
  bf16* qkvw_h = (bf16*)take(3538944);
  bf16* projw_h = (bf16*)take(1179648);
  bf16* fc1w_h = (bf16*)take(4718592);
  bf16* fc2w_h = (bf16*)take(4718592);
  char* regB = take(12582912);                 // hh, later src_f32
  bf16* hh = (bf16*)regB;
  float* src = (float*)regB;
  char* regC = take(37748736);                 // gelu acts + ln1f
  bf16* gact = (bf16*)regC;                    // [0, 25165824) bf16 4096x3072
  float* ln1f = (float*)(regC + 25165824);     // [25165824, 37748736) f32
  bf16* q2h = (bf16*)take(6291456);
  bf16* k2h = (bf16*)take(6291456);
  bf16* vth = (bf16*)take(6291456);
  bf16* oh  = (bf16*)take(6291456);
  bf16* h1v = (bf16*)take(6291456);
  float* Gq = (float*)take(786432);
  float* Gk = (float*)take(786432);
  float* Sq = (float*)take(12288);
  float* Sk = (float*)take(12288);
  float* stats = (float*)take(256);

  const dim3 blk(256);

  (void)hipMemsetAsync((void*)Gq, 0, 786432 * 2 + 12288 * 2 + 256, stream);

  prep<<<dim3(11008), blk, 0, stream>>>(
      qkv_w, proj_w, fc1_w, fc2_w, qkvw_h, projw_h, fc1w_h, fc2w_h,
      x, ln0_w, ln0_b, hh);

  gemm_qkv<<<dim3(36, 32), blk, 0, stream>>>(
      hh, qkvw_h, qkv_b, q2h, k2h, vth, Gq, Gk, Sq, Sk);

  stats_final<<<dim3(4), blk, 0, stream>>>(Gq, Gk, Sq, Sk, stats);

  attn_fused<<<dim3(768), blk, 0, stream>>>(
      q2h, k2h, vth, stats, attn_w, attn_b, out_attn, oh);

  gemm_k<128, 64, 2, 4, 2, 3, EpiProj><<<dim3(12, 32, 1), blk, 0, stream>>>(
      oh, 0, projw_h, 0, 768, 768, 768, EpiProj{proj_b, x, src});

  ln_row<<<dim3(4096), blk, 0, stream>>>(src, ln1_w, ln1_b, h1v, ln1f);

  gemm_k<128, 64, 2, 4, 2, 3, EpiGelu><<<dim3(48, 32, 1), blk, 0, stream>>>(
      h1v, 0, fc1w_h, 0, 768, 768, 768, EpiGelu{fc1_b, gact});

  gemm_k<128, 64, 2, 4, 2, 3, EpiOut><<<dim3(12, 32, 1), blk, 0, stream>>>(
      gact, 0, fc2w_h, 0, 3072, 3072, 3072, EpiOut{fc2_b, ln1f, out_src});
}

// Round 17
// 315.334 us; speedup vs baseline: 1.4707x; 1.4707x over previous
//
#include <hip/hip_runtime.h>

typedef __bf16 bf16;
typedef __bf16 bf16x4 __attribute__((ext_vector_type(4)));
typedef __bf16 bf16x8 __attribute__((ext_vector_type(8)));
typedef float f32x4 __attribute__((ext_vector_type(4)));

#define DEVI __device__ __forceinline__

typedef const __attribute__((address_space(1))) void* gas1;
typedef __attribute__((address_space(3))) void* las3;

// ---------------------------------------------------------------------------
// XCD-chunked bijective block remap (T1, m204 form).
// ---------------------------------------------------------------------------
DEVI int xcd_chunk(int bid, int nwg)
{
  const int q = nwg >> 3, r = nwg & 7;
  const int xcd = bid & 7, rank = bid >> 3;
  return (xcd < r) ? xcd * (q + 1) + rank
                   : r * (q + 1) + (xcd - r) * q + rank;
}

// ---------------------------------------------------------------------------
// Stage a [rows x 64] bf16 tile (row bytes = 128) into LDS via global_load_lds,
// with st-style XOR swizzle (linear LDS dest + pre-swizzled global source).
// ---------------------------------------------------------------------------
DEVI void stage_tile(const bf16* g, int ld, char* lds, int bytes, int tid)
{
  const int wv = tid >> 6, lane = tid & 63;
  const char* gb = (const char*)g;
  const long rowb = (long)ld * 2;
  for (int off = wv * 1024; off < bytes; off += 4096) {
    const int o  = off + lane * 16;                 // linear LDS dest
    const int s  = o ^ (((o >> 7) & 7) << 4);       // pre-swizzled source pos
    const int r  = s >> 7;                          // 128B per tile row
    const int cb = s & 127;
    __builtin_amdgcn_global_load_lds((gas1)(gb + (long)r * rowb + cb),
                                     (las3)(lds + off), 16, 0, 0);
  }
}

template<int N> DEVI void waitvm()
{
  if constexpr (N == 8)      asm volatile("s_waitcnt vmcnt(8)" ::: "memory");
  else if constexpr (N == 6) asm volatile("s_waitcnt vmcnt(6)" ::: "memory");
  else if constexpr (N == 4) asm volatile("s_waitcnt vmcnt(4)" ::: "memory");
  else if constexpr (N == 2) asm volatile("s_waitcnt vmcnt(2)" ::: "memory");
  else                       asm volatile("s_waitcnt vmcnt(0)" ::: "memory");
}

// Wave-local LDS fence: orders ds ops across lanes of ONE wave.
DEVI void wave_lds_fence()
{
  asm volatile("s_waitcnt lgkmcnt(0)" ::: "memory");
  __builtin_amdgcn_sched_barrier(0);
}

// ---------------------------------------------------------------------------
// Epilogue functors
// ---------------------------------------------------------------------------
struct EpiProj {
  const float* bias; const float* x; float* src;
  DEVI void operator()(int z, int row, int col, float v) const {
    const long i = (long)row * 768 + col;
    src[i] = v + bias[col] + x[i];
  }
};

struct EpiGelu {
  const float* bias; bf16* g;
  DEVI void operator()(int z, int row, int col, float v) const {
    const float t = v + bias[col];
    const float r = 0.5f * t * (1.0f + erff(t * 0.70710678118654752f));
    g[(long)row * 3072 + col] = (bf16)r;
  }
};

struct EpiOut {
  const float* bias; const float* lnf; float* outp;
  DEVI void operator()(int z, int row, int col, float v) const {
    const long i = (long)row * 768 + col;
    outp[i] = v + bias[col] + lnf[i];   // final residual uses POST-LN1 src
  }
};

// ---------------------------------------------------------------------------
// bf16 GEMM, 2-phase double-buffered, counted vmcnt; XCD-chunked.
// 128x64 tiles, 4 waves (2x2), FM=4 FN=2. LDS 48KB -> 3 blocks/CU.
// ---------------------------------------------------------------------------
template<int BM, int BN, int WC, int FM, int FN, int WPE, class Epi>
__global__ __launch_bounds__(256, WPE) void gemm_k(
    const bf16* __restrict__ A, long abatch,
    const bf16* __restrict__ B, long bbatch,
    int lda, int ldb, int K, Epi epi)
{
  constexpr int BK = 64;
  constexpr int AB = BM * BK * 2, BB = BN * BK * 2;
  constexpr int BUFB = AB + BB;
  constexpr int LPS = BUFB / 4096;          // global_load_lds per wave per stage
  __shared__ char smem[2 * BUFB];

  const int tid = threadIdx.x, lane = tid & 63, wv = tid >> 6;
  const int wr = wv / WC, wc = wv % WC;
  const int NT = gridDim.x;
  const int nwg = NT * gridDim.y;
  const int wid = xcd_chunk(blockIdx.y * NT + blockIdx.x, nwg);
  const int mt = wid / NT, nt = wid % NT;
  const int z = blockIdx.z;
  const long abase = (long)z * abatch + (long)mt * BM * lda;
  const long bbase = (long)z * bbatch + (long)nt * BN * ldb;
  const int l15 = lane & 15;
  const int sw = (lane & 7) << 4;           // per-lane read swizzle

  auto stage_all = [&](int buf, int kt) {
    char* base = smem + buf * BUFB;
    stage_tile(A + abase + kt, lda, base, AB, tid);
    stage_tile(B + bbase + kt, ldb, base + AB, BB, tid);
  };

  f32x4 acc[FM][FN];
#pragma unroll
  for (int m = 0; m < FM; ++m)
#pragma unroll
    for (int n = 0; n < FN; ++n) acc[m][n] = f32x4{0.f, 0.f, 0.f, 0.f};

  const int arow = wr * FM * 16, bcol = wc * FN * 16;
  const int T = K / BK;

  stage_all(0, 0);
  int cur = 0;
  for (int t = 0; t < T; ++t) {
    if (t + 1 < T) { stage_all(cur ^ 1, (t + 1) * BK); waitvm<LPS>(); }
    else           { waitvm<0>(); }
    __builtin_amdgcn_s_barrier();
    asm volatile("" ::: "memory");

    const char* As = smem + cur * BUFB;
    const char* Bs = As + AB;
#pragma unroll
    for (int ks = 0; ks < 2; ++ks) {
      const int ko = (ks * 64 + (lane >> 4) * 16) ^ sw;
      bf16x8 av[FM], bv[FN];
#pragma unroll
      for (int m = 0; m < FM; ++m)
        av[m] = *(const bf16x8*)(As + (arow + m * 16 + l15) * 128 + ko);
#pragma unroll
      for (int n = 0; n < FN; ++n)
        bv[n] = *(const bf16x8*)(Bs + (bcol + n * 16 + l15) * 128 + ko);
#pragma unroll
      for (int m = 0; m < FM; ++m)
#pragma unroll
        for (int n = 0; n < FN; ++n)
          acc[m][n] = __builtin_amdgcn_mfma_f32_16x16x32_bf16(av[m], bv[n], acc[m][n], 0, 0, 0);
    }
    asm volatile("s_waitcnt lgkmcnt(0)" ::: "memory");   // LDS reads done
    __builtin_amdgcn_s_barrier();                         // before buf reuse
    asm volatile("" ::: "memory");
    cur ^= 1;
  }

#pragma unroll
  for (int m = 0; m < FM; ++m)
#pragma unroll
    for (int n = 0; n < FN; ++n)
#pragma unroll
      for (int r = 0; r < 4; ++r) {
        const int grow = mt * BM + arow + m * 16 + (lane >> 4) * 4 + r;
        const int gcol = nt * BN + bcol + n * 16 + l15;
        epi(z, grow, gcol, acc[m][n][r]);
      }
}

// ---------------------------------------------------------------------------
// QKV GEMM with FUSED qkv_post epilogue + FUSED Gram stats (R15 known-good).
// ---------------------------------------------------------------------------
__global__ __launch_bounds__(256, 3) void gemm_qkv(
    const bf16* __restrict__ A, const bf16* __restrict__ B,
    const float* __restrict__ bias, bf16* __restrict__ q2h,
    bf16* __restrict__ k2h, bf16* __restrict__ vth,
    float* __restrict__ Gq, float* __restrict__ Gk,
    float* __restrict__ Sq, float* __restrict__ Sk)
{
  constexpr int BM = 128, BN = 64, BK = 64;
  constexpr int AB = BM * BK * 2, BB = BN * BK * 2;
  constexpr int BUFB = AB + BB;
  constexpr int LPS = BUFB / 4096;
  __shared__ char smem[2 * BUFB];
  __shared__ float rowsum[2][BM];

  const int tid = threadIdx.x, lane = tid & 63, wv = tid >> 6;
  const int wr = wv >> 1, wc = wv & 1;
  const int NT = 36;
  const int wid = xcd_chunk(blockIdx.y * NT + blockIdx.x, NT * 32);
  const int mt = wid / NT, nt = wid % NT;
  const int sec = nt / 12, h = nt - sec * 12;
  const long abase = (long)mt * BM * 768;
  const long bbase = (long)nt * BN * 768;
  const int l15 = lane & 15, lhi = lane >> 4;
  const int sw = (lane & 7) << 4;

  auto stage_all = [&](int buf, int kt) {
    char* base = smem + buf * BUFB;
    stage_tile(A + abase + kt, 768, base, AB, tid);
    stage_tile(B + bbase + kt, 768, base + AB, BB, tid);
  };

  f32x4 acc[4][2];
#pragma unroll
  for (int m = 0; m < 4; ++m)
#pragma unroll
    for (int n = 0; n < 2; ++n) acc[m][n] = f32x4{0.f, 0.f, 0.f, 0.f};

  const int arow = wr * 64, bcol = wc * 32;

  stage_all(0, 0);
  int cur = 0;
  for (int t = 0; t < 12; ++t) {
    if (t + 1 < 12) { stage_all(cur ^ 1, (t + 1) * BK); waitvm<LPS>(); }
    else            { waitvm<0>(); }
    __builtin_amdgcn_s_barrier();
    asm volatile("" ::: "memory");

    const char* As = smem + cur * BUFB;
    const char* Bs = As + AB;
#pragma unroll
    for (int ks = 0; ks < 2; ++ks) {
      const int ko = (ks * 64 + lhi * 16) ^ sw;
      bf16x8 av[4], bv[2];
#pragma unroll
      for (int m = 0; m < 4; ++m)
        av[m] = *(const bf16x8*)(As + (arow + m * 16 + l15) * 128 + ko);
#pragma unroll
      for (int n = 0; n < 2; ++n)
        bv[n] = *(const bf16x8*)(Bs + (bcol + n * 16 + l15) * 128 + ko);
#pragma unroll
      for (int m = 0; m < 4; ++m)
#pragma unroll
        for (int n = 0; n < 2; ++n)
          acc[m][n] = __builtin_amdgcn_mfma_f32_16x16x32_bf16(av[m], bv[n], acc[m][n], 0, 0, 0);
    }
    asm volatile("s_waitcnt lgkmcnt(0)" ::: "memory");
    __builtin_amdgcn_s_barrier();
    asm volatile("" ::: "memory");
    cur ^= 1;
  }

  // ---- fused epilogue ----
  float val[4][2][4];
#pragma unroll
  for (int m = 0; m < 4; ++m)
#pragma unroll
    for (int n = 0; n < 2; ++n)
#pragma unroll
      for (int r = 0; r < 4; ++r)
        val[m][n][r] = acc[m][n][r] + bias[nt * 64 + bcol + n * 16 + l15];

  if (sec < 2) {
#pragma unroll
    for (int m = 0; m < 4; ++m)
#pragma unroll
      for (int r = 0; r < 4; ++r) {
        float p = val[m][0][r] * val[m][0][r] + val[m][1][r] * val[m][1][r];
        p += __shfl_xor(p, 1);
        p += __shfl_xor(p, 2);
        p += __shfl_xor(p, 4);
        p += __shfl_xor(p, 8);
        if (l15 == 0) rowsum[wc][arow + m * 16 + lhi * 4 + r] = p;
      }
    __syncthreads();

    bf16* dst = (sec == 0) ? q2h : k2h;
    float* G  = (sec == 0) ? Gq  : Gk;
    float* S  = (sec == 0) ? Sq  : Sk;
    const int bq = mt >> 3;
    const int z = bq * 12 + h;
    char* T0 = smem;            // [64 d][128B] swizzled, rows n' 0..63
    char* T1 = smem + 8192;     //                       rows n' 64..127
    float colsum[2] = {0.f, 0.f};
#pragma unroll
    for (int m = 0; m < 4; ++m)
#pragma unroll
      for (int r = 0; r < 4; ++r) {
        const int row = arow + m * 16 + lhi * 4 + r;     // 0..127
        const float inv = 1.0f / (rowsum[0][row] + rowsum[1][row]);
        const int grow = mt * BM + row;
        const int nn = grow & 1023;
        const long base = (((long)z) * 1024 + nn) * 64;
        char* Tt = (row & 64) ? T1 : T0;
        const int np = row & 63;
#pragma unroll
        for (int n = 0; n < 2; ++n) {
          const float v = val[m][n][r];
          const int d = bcol + n * 16 + l15;
          const bf16 q2b = (bf16)(v * v * inv);
          dst[base + d] = q2b;
          *(bf16*)(Tt + d * 128 + ((np * 2) ^ ((d & 7) << 4))) = q2b;
          colsum[n] += (float)q2b;
        }
      }
    // Sq/Sk: reduce over lhi (this wave's 64 rows), cross-wr via atomics.
#pragma unroll
    for (int n = 0; n < 2; ++n) {
      float s = colsum[n];
      s += __shfl_xor(s, 16);
      s += __shfl_xor(s, 32);
      if (lane < 16) atomicAdd(&S[z * 64 + bcol + n * 16 + l15], s);
    }
    __syncthreads();   // T fully written (all waves) before Gram reads

    // Gram: G[d][e] += sum_n q2[n][d]*q2[n][e]; wave wv owns 4 of 16 tiles.
#pragma unroll
    for (int gi = 0; gi < 4; ++gi) {
      const int g = wv * 4 + gi;
      const int dr = g >> 2, ec = g & 3;
      f32x4 ga = f32x4{0.f, 0.f, 0.f, 0.f};
#pragma unroll
      for (int ks = 0; ks < 4; ++ks) {
        const char* Tt = (ks & 2) ? T1 : T0;
        const int ko = ((ks & 1) * 64 + lhi * 16) ^ sw;
        const bf16x8 av = *(const bf16x8*)(Tt + (dr * 16 + l15) * 128 + ko);
        const bf16x8 bv = *(const bf16x8*)(Tt + (ec * 16 + l15) * 128 + ko);
        ga = __builtin_amdgcn_mfma_f32_16x16x32_bf16(av, bv, ga, 0, 0, 0);
      }
#pragma unroll
      for (int r = 0; r < 4; ++r)
        atomicAdd(&G[(long)z * 4096 + (dr * 16 + lhi * 4 + r) * 64 + ec * 16 + l15],
                  ga[r]);
    }
  } else {
    // v-section: transpose the 128(n) x 64(d) tile through LDS, then
    // coalesced bf16x8 stores to vth[(b*12+h)*64 + d][nn0 + c].
    bf16* T = (bf16*)smem;             // [64 d][pitch 144] (post-loop reuse)
#pragma unroll
    for (int m = 0; m < 4; ++m)
#pragma unroll
      for (int n = 0; n < 2; ++n)
#pragma unroll
        for (int r = 0; r < 4; ++r) {
          const int row = arow + m * 16 + lhi * 4 + r;   // 0..127 (n)
          const int col = bcol + n * 16 + l15;           // 0..63  (d)
          T[col * 144 + row] = (bf16)val[m][n][r];
        }
    __syncthreads();
    const int bq = mt >> 3, nn0 = (mt & 7) * 128;
    const long basez = ((long)(bq * 12 + h) * 64) * 1024;
#pragma unroll
    for (int it = 0; it < 4; ++it) {
      const int flat = it * 2048 + tid * 8;
      const int d = flat >> 7, c = flat & 127;
      const bf16x8 o = *(const bf16x8*)&T[d * 144 + c];
      *(bf16x8*)&vth[basez + (long)d * 1024 + nn0 + c] = o;
    }
  }
}

// ---------------------------------------------------------------------------
// Fused attention tail — R15 known-good form (REVERT of R16's Q-in-regs:
// launch_bounds(256,4) capped VGPR at 64 and the kernel's ~100 VGPRs spilled
// to scratch — WRITE_SIZE showed +70MB spill traffic, 2.5x slowdown).
// Qs in LDS; 48KB -> 3 blocks/CU; VGPR ~88, no spill.
// Counted vmcnt(4) store drain + one-iter-ahead wn/bn prefetch.
// ---------------------------------------------------------------------------
__global__ __launch_bounds__(256, 3) void attn_fused(
    const bf16* __restrict__ q2h, const bf16* __restrict__ k2h,
    const bf16* __restrict__ vth, const float* __restrict__ stats,
    const float* __restrict__ wn, const float* __restrict__ bn,
    float* __restrict__ attn_out, bf16* __restrict__ oh)
{
  __shared__ char smem[49152];
  char* Qs  = smem;                    //  8KB  64x64 bf16 (swizzled)
  char* Ks0 = smem + 8192;
  char* Ks1 = smem + 16384;
  char* Vs0 = smem + 24576;
  char* Vs1 = smem + 32768;
  char* Pall = smem + 40960;           //  8KB: 4 waves x [16][64] bf16 (swz)

  const int tid = threadIdx.x, lane = tid & 63, wv = tid >> 6;
  const int wid = xcd_chunk(blockIdx.x, 768);
  const int b = wid & 3;               // fastest: wn/bn strip sharing
  const int mt = (wid >> 2) & 15;
  const int h = wid >> 6;
  const int zq = b * 12 + h;
  const float mu = stats[2 * b], rs = stats[2 * b + 1];
  const int l15 = lane & 15, lhi = lane >> 4;
  const int sw = (lane & 7) << 4;
  char* Ps = Pall + wv * 2048;         // wave-private [16 rows][128B]

  const long zoff = (long)zq * 65536;

  auto load_wb = [&](int nt, f32x4* wreg, f32x4* breg) {
#pragma unroll
    for (int rr = 0; rr < 4; ++rr) {
      const long grow = (long)mt * 64 + wv * 16 + rr * 4 + lhi;
      const long gcol = (long)nt * 64 + l15 * 4;
      wreg[rr] = *(const f32x4*)&wn[((long)h * 1024 + grow) * 1024 + gcol];
      breg[rr] = *(const f32x4*)&bn[((long)h * 1024 + grow) * 1024 + gcol];
    }
  };

  f32x4 wcur[4], bcur[4];
  load_wb(0, wcur, bcur);
  stage_tile(q2h + zoff + (long)mt * 4096, 64, Qs, 8192, tid);
  stage_tile(k2h + zoff, 64, Ks0, 8192, tid);
  stage_tile(vth + zoff, 1024, Vs0, 8192, tid);
  __syncthreads();

  f32x4 oacc[4];
#pragma unroll
  for (int n = 0; n < 4; ++n) oacc[n] = f32x4{0.f, 0.f, 0.f, 0.f};

  for (int nt = 0; nt < 16; ++nt) {
    const int cur = nt & 1;
    char* Kc = cur ? Ks1 : Ks0;
    char* Vc = cur ? Vs1 : Vs0;
    char* Kn = cur ? Ks0 : Ks1;
    char* Vn = cur ? Vs0 : Vs1;

    // next-iter prefetch: wn/bn to regs, then K/V DMA (counted at iter end).
    f32x4 wnx[4], bnx[4];
    if (nt + 1 < 16) {
      load_wb(nt + 1, wnx, bnx);
      stage_tile(k2h + zoff + (long)(nt + 1) * 4096, 64, Kn, 8192, tid);
      stage_tile(vth + zoff + (nt + 1) * 64, 1024, Vn, 8192, tid);
    }

    // ---- QK^T: wave computes its 16 rows x all 64 cols ----
    f32x4 acc[4];
#pragma unroll
    for (int n = 0; n < 4; ++n) acc[n] = f32x4{0.f, 0.f, 0.f, 0.f};
    __builtin_amdgcn_s_setprio(1);
#pragma unroll
    for (int ks = 0; ks < 2; ++ks) {
      const int ko = (ks * 64 + lhi * 16) ^ sw;
      const bf16x8 av = *(const bf16x8*)(Qs + (wv * 16 + l15) * 128 + ko);
#pragma unroll
      for (int n = 0; n < 4; ++n) {
        const bf16x8 bv = *(const bf16x8*)(Kc + (n * 16 + l15) * 128 + ko);
        acc[n] = __builtin_amdgcn_mfma_f32_16x16x32_bf16(av, bv, acc[n], 0, 0, 0);
      }
    }
    __builtin_amdgcn_s_setprio(0);
    // s_ln = (s-mu)*rs -> bf16, into wave-private Ps (swizzled).
#pragma unroll
    for (int n = 0; n < 4; ++n)
#pragma unroll
      for (int r = 0; r < 4; ++r) {
        const int row = lhi * 4 + r;                 // local row 0..15
        const int cb = (n * 32 + l15 * 2) ^ ((row & 7) << 4);
        *(bf16*)(Ps + row * 128 + cb) = (bf16)((acc[n][r] - mu) * rs);
      }
    wave_lds_fence();  // cross-lane RAW within wave: QK^T writes -> LN reads

    // ---- LN: r = s_ln*w + b -> attn_out f32x4 (coalesced) + Ps in-place ----
#pragma unroll
    for (int rr = 0; rr < 4; ++rr) {
      const int row = rr * 4 + lhi;                  // local row 0..15
      const int cb = (l15 * 8) ^ ((row & 7) << 4);
      const bf16x4 s4 = *(const bf16x4*)(Ps + row * 128 + cb);
      const long grow = (long)mt * 64 + wv * 16 + row;
      const long gcol = (long)nt * 64 + l15 * 4;
      f32x4 r4;
      bf16x4 h4;
#pragma unroll
      for (int e = 0; e < 4; ++e) {
        const float r = (float)s4[e] * wcur[rr][e] + bcur[rr][e];
        r4[e] = r;
        h4[e] = (bf16)r;
      }
      *(f32x4*)&attn_out[((long)zq * 1024 + grow) * 1024 + gcol] = r4;
      *(bf16x4*)(Ps + row * 128 + cb) = h4;
    }
    wave_lds_fence();  // cross-lane RAW within wave: LN write-back -> PV reads

    // ---- PV: o[row, d] += sum_j P[row,j] vT[d,j] ----
    __builtin_amdgcn_s_setprio(1);
#pragma unroll
    for (int ks = 0; ks < 2; ++ks) {
      const int ko = (ks * 64 + lhi * 16) ^ sw;
      const bf16x8 av = *(const bf16x8*)(Ps + l15 * 128 + ko);
#pragma unroll
      for (int n = 0; n < 4; ++n) {
        const bf16x8 bv = *(const bf16x8*)(Vc + (n * 16 + l15) * 128 + ko);
        oacc[n] = __builtin_amdgcn_mfma_f32_16x16x32_bf16(av, bv, oacc[n], 0, 0, 0);
      }
    }
    __builtin_amdgcn_s_setprio(0);
    // counted drain: the 4 newest VMEM ops (attn stores) may stay in flight;
    // everything older (K/V DMA + wb loads) is forced complete.
    waitvm<4>();
    __builtin_amdgcn_s_barrier();
    asm volatile("" ::: "memory");

    if (nt + 1 < 16) {
#pragma unroll
      for (int rr = 0; rr < 4; ++rr) { wcur[rr] = wnx[rr]; bcur[rr] = bnx[rr]; }
    }
  }

  // ---- epilogue: o -> (B,N,C) bf16 ----
#pragma unroll
  for (int n = 0; n < 4; ++n)
#pragma unroll
    for (int r = 0; r < 4; ++r) {
      const int row = mt * 64 + wv * 16 + lhi * 4 + r;
      const int col = n * 16 + l15;
      oh[((long)(b * 1024 + row)) * 768 + h * 64 + col] = (bf16)oacc[n][r];
    }
}

// ---------------------------------------------------------------------------
// prep: all four weight casts + LN0 in ONE launch (block-range split).
// ---------------------------------------------------------------------------
__global__ __launch_bounds__(256) void prep(
    const float* __restrict__ qkvw, const float* __restrict__ projw,
    const float* __restrict__ fc1w, const float* __restrict__ fc2w,
    bf16* __restrict__ dq, bf16* __restrict__ dp,
    bf16* __restrict__ d1, bf16* __restrict__ d2,
    const float* __restrict__ x, const float* __restrict__ w,
    const float* __restrict__ bb, bf16* __restrict__ outh)
{
  __shared__ float red[256];
  const int bid = blockIdx.x, tid = threadIdx.x;
  if (bid < 6912) {
    const int i = bid * 256 + tid;     // n4 index over 1769472
    const float* s; bf16* d; int off;
    if (i < 442368)       { s = qkvw; d = dq; off = i; }
    else if (i < 589824)  { s = projw; d = dp; off = i - 442368; }
    else if (i < 1179648) { s = fc1w; d = d1; off = i - 589824; }
    else                  { s = fc2w; d = d2; off = i - 1179648; }
    const f32x4 v = *(const f32x4*)&s[(long)off * 4];
    bf16x4 o;
#pragma unroll
    for (int j = 0; j < 4; ++j) o[j] = (bf16)v[j];
    *(bf16x4*)&d[(long)off * 4] = o;
  } else {
    const int row = bid - 6912;
    const float* p = x + (long)row * 768;
    const float v0 = p[tid], v1 = p[tid + 256], v2 = p[tid + 512];
    red[tid] = v0 + v1 + v2;
    __syncthreads();
    for (int st = 128; st > 0; st >>= 1) { if (tid < st) red[tid] += red[tid + st]; __syncthreads(); }
    const float mu = red[0] * (1.0f / 768.0f);
    __syncthreads();
    const float d0 = v0 - mu, d1v = v1 - mu, d2v = v2 - mu;
    red[tid] = d0 * d0 + d1v * d1v + d2v * d2v;
    __syncthreads();
    for (int st = 128; st > 0; st >>= 1) { if (tid < st) red[tid] += red[tid + st]; __syncthreads(); }
    const float rs = rsqrtf(red[0] * (1.0f / 768.0f) + 1e-5f);
    const float dv[3] = {d0, d1v, d2v};
#pragma unroll
    for (int k = 0; k < 3; ++k) {
      const int c = tid + k * 256;
      outh[(long)row * 768 + c] = (bf16)(dv[k] * rs * w[c] + bb[c]);
    }
  }
}

// LayerNorm over rows of 768; writes bf16 (+ optional f32). (LN1)
__global__ __launch_bounds__(256) void ln_row(
    const float* __restrict__ in, const float* __restrict__ w,
    const float* __restrict__ b, bf16* __restrict__ outh,
    float* __restrict__ outf)
{
  __shared__ float red[256];
  const int row = blockIdx.x, tid = threadIdx.x;
  const float* p = in + (long)row * 768;
  const float v0 = p[tid], v1 = p[tid + 256], v2 = p[tid + 512];
  red[tid] = v0 + v1 + v2;
  __syncthreads();
  for (int st = 128; st > 0; st >>= 1) { if (tid < st) red[tid] += red[tid + st]; __syncthreads(); }
  const float mu = red[0] * (1.0f / 768.0f);
  __syncthreads();
  const float d0 = v0 - mu, d1 = v1 - mu, d2 = v2 - mu;
  red[tid] = d0 * d0 + d1 * d1 + d2 * d2;
  __syncthreads();
  for (int st = 128; st > 0; st >>= 1) { if (tid < st) red[tid] += red[tid + st]; __syncthreads(); }
  const float rs = rsqrtf(red[0] * (1.0f / 768.0f) + 1e-5f);
  const float dv[3] = {d0, d1, d2};
#pragma unroll
  for (int k = 0; k < 3; ++k) {
    const int c = tid + k * 256;
    const float h = dv[k] * rs * w[c] + b[c];
    outh[(long)row * 768 + c] = (bf16)h;
    if (outf) outf[(long)row * 768 + c] = h;
  }
}

// Per-batch mean / rstd of the attn tensor from Gram partials.
__global__ __launch_bounds__(256) void stats_final(
    const float* __restrict__ Gq, const float* __restrict__ Gk,
    const float* __restrict__ Sq, const float* __restrict__ Sk,
    float* __restrict__ stats)
{
  __shared__ double red[256];
  const int b = blockIdx.x, tid = threadIdx.x;
  double s2 = 0.0, s1 = 0.0;
  for (int h = 0; h < 12; ++h) {
    const float* gq = Gq + ((long)(b * 12 + h)) * 4096;
    const float* gk = Gk + ((long)(b * 12 + h)) * 4096;
    for (int i = tid; i < 4096; i += 256) s2 += (double)gq[i] * (double)gk[i];
    const float* sqp = Sq + (b * 12 + h) * 64;
    const float* skp = Sk + (b * 12 + h) * 64;
    for (int i = tid; i < 64; i += 256) s1 += (double)sqp[i] * (double)skp[i];
  }
  red[tid] = s2; __syncthreads();
  for (int st = 128; st > 0; st >>= 1) { if (tid < st) red[tid] += red[tid + st]; __syncthreads(); }
  const double S2 = red[0]; __syncthreads();
  red[tid] = s1; __syncthreads();
  for (int st = 128; st > 0; st >>= 1) { if (tid < st) red[tid] += red[tid + st]; __syncthreads(); }
  if (tid == 0) {
    const double S1 = red[0];
    const double cnt = 12.0 * 1024.0 * 1024.0;
    const double mean = S1 / cnt;
    const double var = S2 / cnt - mean * mean;
    stats[2 * b] = (float)mean;
    stats[2 * b + 1] = (float)(1.0 / sqrt(var + 1e-5));
  }
}

// ---------------------------------------------------------------------------
extern "C" void kernel_launch(void* const* d_in, const int* in_sizes, int n_in,
                              void* d_out, int out_size, void* d_ws, size_t ws_size,
                              hipStream_t stream)
{
  const float* x      = (const float*)d_in[0];
  const float* ln0_w  = (const float*)d_in[1];
  const float* ln0_b  = (const float*)d_in[2];
  const float* qkv_w  = (const float*)d_in[3];
  const float* qkv_b  = (const float*)d_in[4];
  const float* proj_w = (const float*)d_in[5];
  const float* proj_b = (const float*)d_in[6];
  const float* attn_w = (const float*)d_in[7];
  const float* attn_b = (const float*)d_in[8];
  const float* ln1_w  = (const float*)d_in[9];
  const float* ln1_b  = (const float*)d_in[10];
  const float* fc1_w  = (const float*)d_in[11];
  const float* fc1_b  = (const float*)d_in[12];
  const float* fc2_w  = (const float*)d_in[13];
  const float* fc2_b  = (const float*)d_in[14];

  float* out_src  = (float*)d_out;
  float* out_attn = out_src + 4L * 1024 * 768;       // 3145728

  char* p = (char*)d_ws;
  auto take = [&](long bytes) -> char* {
    char* r = p;
    p += (bytes + 255) & ~255L;
    return r;
  };
  bf16* qkvw_h = (bf16*)take(3538944);
  bf16* projw_h = (bf16*)take(1179648);
  bf16* fc1w_h = (bf16*)take(4718592);
  bf16* fc2w_h = (bf16*)take(4718592);
  char* regB = take(12582912);                 // hh, later src_f32
  bf16* hh = (bf16*)regB;
  float* src = (float*)regB;
  char* regC = take(37748736);                 // gelu acts + ln1f
  bf16* gact = (bf16*)regC;                    // [0, 25165824) bf16 4096x3072
  float* ln1f = (float*)(regC + 25165824);     // [25165824, 37748736) f32
  bf16* q2h = (bf16*)take(6291456);
  bf16* k2h = (bf16*)take(6291456);
  bf16* vth = (bf16*)take(6291456);
  bf16* oh  = (bf16*)take(6291456);
  bf16* h1v = (bf16*)take(6291456);
  float* Gq = (float*)take(786432);
  float* Gk = (float*)take(786432);
  float* Sq = (float*)take(12288);
  float* Sk = (float*)take(12288);
  float* stats = (float*)take(256);

  const dim3 blk(256);

  (void)hipMemsetAsync((void*)Gq, 0, 786432 * 2 + 12288 * 2 + 256, stream);

  prep<<<dim3(11008), blk, 0, stream>>>(
      qkv_w, proj_w, fc1_w, fc2_w, qkvw_h, projw_h, fc1w_h, fc2w_h,
      x, ln0_w, ln0_b, hh);

  gemm_qkv<<<dim3(36, 32), blk, 0, stream>>>(
      hh, qkvw_h, qkv_b, q2h, k2h, vth, Gq, Gk, Sq, Sk);

  stats_final<<<dim3(4), blk, 0, stream>>>(Gq, Gk, Sq, Sk, stats);

  attn_fused<<<dim3(768), blk, 0, stream>>>(
      q2h, k2h, vth, stats, attn_w, attn_b, out_attn, oh);

  gemm_k<128, 64, 2, 4, 2, 3, EpiProj><<<dim3(12, 32, 1), blk, 0, stream>>>(
      oh, 0, projw_h, 0, 768, 768, 768, EpiProj{proj_b, x, src});

  ln_row<<<dim3(4096), blk, 0, stream>>>(src, ln1_w, ln1_b, h1v, ln1f);

  gemm_k<128, 64, 2, 4, 2, 3, EpiGelu><<<dim3(48, 32, 1), blk, 0, stream>>>(
      h1v, 0, fc1w_h, 0, 768, 768, 768, EpiGelu{fc1_b, gact});

  gemm_k<128, 64, 2, 4, 2, 3, EpiOut><<<dim3(12, 32, 1), blk, 0, stream>>>(
      gact, 0, fc2w_h, 0, 3072, 3072, 3072, EpiOut{fc2_b, ln1f, out_src});
}

// Round 18
// 314.624 us; speedup vs baseline: 1.4740x; 1.0023x over previous
//
#include <hip/hip_runtime.h>

typedef __bf16 bf16;
typedef __bf16 bf16x4 __attribute__((ext_vector_type(4)));
typedef __bf16 bf16x8 __attribute__((ext_vector_type(8)));
typedef float f32x4 __attribute__((ext_vector_type(4)));

#define DEVI __device__ __forceinline__

typedef const __attribute__((address_space(1))) void* gas1;
typedef __attribute__((address_space(3))) void* las3;

// ---------------------------------------------------------------------------
// XCD-chunked bijective block remap (T1, m204 form).
// ---------------------------------------------------------------------------
DEVI int xcd_chunk(int bid, int nwg)
{
  const int q = nwg >> 3, r = nwg & 7;
  const int xcd = bid & 7, rank = bid >> 3;
  return (xcd < r) ? xcd * (q + 1) + rank
                   : r * (q + 1) + (xcd - r) * q + rank;
}

// ---------------------------------------------------------------------------
// Stage a [rows x 64] bf16 tile (row bytes = 128) into LDS via global_load_lds,
// with st-style XOR swizzle (linear LDS dest + pre-swizzled global source).
// ---------------------------------------------------------------------------
DEVI void stage_tile(const bf16* g, int ld, char* lds, int bytes, int tid)
{
  const int wv = tid >> 6, lane = tid & 63;
  const char* gb = (const char*)g;
  const long rowb = (long)ld * 2;
  for (int off = wv * 1024; off < bytes; off += 4096) {
    const int o  = off + lane * 16;                 // linear LDS dest
    const int s  = o ^ (((o >> 7) & 7) << 4);       // pre-swizzled source pos
    const int r  = s >> 7;                          // 128B per tile row
    const int cb = s & 127;
    __builtin_amdgcn_global_load_lds((gas1)(gb + (long)r * rowb + cb),
                                     (las3)(lds + off), 16, 0, 0);
  }
}

template<int N> DEVI void waitvm()
{
  if constexpr (N == 8)      asm volatile("s_waitcnt vmcnt(8)" ::: "memory");
  else if constexpr (N == 6) asm volatile("s_waitcnt vmcnt(6)" ::: "memory");
  else if constexpr (N == 4) asm volatile("s_waitcnt vmcnt(4)" ::: "memory");
  else if constexpr (N == 2) asm volatile("s_waitcnt vmcnt(2)" ::: "memory");
  else                       asm volatile("s_waitcnt vmcnt(0)" ::: "memory");
}

// Wave-local LDS fence: orders ds ops across lanes of ONE wave.
DEVI void wave_lds_fence()
{
  asm volatile("s_waitcnt lgkmcnt(0)" ::: "memory");
  __builtin_amdgcn_sched_barrier(0);
}

// ---------------------------------------------------------------------------
// Epilogue functors
// ---------------------------------------------------------------------------
struct EpiProj {
  const float* bias; const float* x; float* src;
  DEVI void operator()(int z, int row, int col, float v) const {
    const long i = (long)row * 768 + col;
    src[i] = v + bias[col] + x[i];
  }
};

struct EpiGelu {
  const float* bias; bf16* g;
  DEVI void operator()(int z, int row, int col, float v) const {
    const float t = v + bias[col];
    const float r = 0.5f * t * (1.0f + erff(t * 0.70710678118654752f));
    g[(long)row * 3072 + col] = (bf16)r;
  }
};

struct EpiOut {
  const float* bias; const float* lnf; float* outp;
  DEVI void operator()(int z, int row, int col, float v) const {
    const long i = (long)row * 768 + col;
    outp[i] = v + bias[col] + lnf[i];   // final residual uses POST-LN1 src
  }
};

// ---------------------------------------------------------------------------
// bf16 GEMM, 2-phase double-buffered, counted vmcnt; XCD-chunked.
// Tiles BMxBN, 4 waves; LPS = BUFB/4096 in {4, 6}.
// ---------------------------------------------------------------------------
template<int BM, int BN, int WC, int FM, int FN, int WPE, class Epi>
__global__ __launch_bounds__(256, WPE) void gemm_k(
    const bf16* __restrict__ A, long abatch,
    const bf16* __restrict__ B, long bbatch,
    int lda, int ldb, int K, Epi epi)
{
  constexpr int BK = 64;
  constexpr int AB = BM * BK * 2, BB = BN * BK * 2;
  constexpr int BUFB = AB + BB;
  constexpr int LPS = BUFB / 4096;          // global_load_lds per wave per stage
  __shared__ char smem[2 * BUFB];

  const int tid = threadIdx.x, lane = tid & 63, wv = tid >> 6;
  const int wr = wv / WC, wc = wv % WC;
  const int NT = gridDim.x;
  const int nwg = NT * gridDim.y;
  const int wid = xcd_chunk(blockIdx.y * NT + blockIdx.x, nwg);
  const int mt = wid / NT, nt = wid % NT;
  const int z = blockIdx.z;
  const long abase = (long)z * abatch + (long)mt * BM * lda;
  const long bbase = (long)z * bbatch + (long)nt * BN * ldb;
  const int l15 = lane & 15;
  const int sw = (lane & 7) << 4;           // per-lane read swizzle

  auto stage_all = [&](int buf, int kt) {
    char* base = smem + buf * BUFB;
    stage_tile(A + abase + kt, lda, base, AB, tid);
    stage_tile(B + bbase + kt, ldb, base + AB, BB, tid);
  };

  f32x4 acc[FM][FN];
#pragma unroll
  for (int m = 0; m < FM; ++m)
#pragma unroll
    for (int n = 0; n < FN; ++n) acc[m][n] = f32x4{0.f, 0.f, 0.f, 0.f};

  const int arow = wr * FM * 16, bcol = wc * FN * 16;
  const int T = K / BK;

  stage_all(0, 0);
  int cur = 0;
  for (int t = 0; t < T; ++t) {
    if (t + 1 < T) { stage_all(cur ^ 1, (t + 1) * BK); waitvm<LPS>(); }
    else           { waitvm<0>(); }
    __builtin_amdgcn_s_barrier();
    asm volatile("" ::: "memory");

    const char* As = smem + cur * BUFB;
    const char* Bs = As + AB;
#pragma unroll
    for (int ks = 0; ks < 2; ++ks) {
      const int ko = (ks * 64 + (lane >> 4) * 16) ^ sw;
      bf16x8 av[FM], bv[FN];
#pragma unroll
      for (int m = 0; m < FM; ++m)
        av[m] = *(const bf16x8*)(As + (arow + m * 16 + l15) * 128 + ko);
#pragma unroll
      for (int n = 0; n < FN; ++n)
        bv[n] = *(const bf16x8*)(Bs + (bcol + n * 16 + l15) * 128 + ko);
#pragma unroll
      for (int m = 0; m < FM; ++m)
#pragma unroll
        for (int n = 0; n < FN; ++n)
          acc[m][n] = __builtin_amdgcn_mfma_f32_16x16x32_bf16(av[m], bv[n], acc[m][n], 0, 0, 0);
    }
    asm volatile("s_waitcnt lgkmcnt(0)" ::: "memory");   // LDS reads done
    __builtin_amdgcn_s_barrier();                         // before buf reuse
    asm volatile("" ::: "memory");
    cur ^= 1;
  }

#pragma unroll
  for (int m = 0; m < FM; ++m)
#pragma unroll
    for (int n = 0; n < FN; ++n)
#pragma unroll
      for (int r = 0; r < 4; ++r) {
        const int grow = mt * BM + arow + m * 16 + (lane >> 4) * 4 + r;
        const int gcol = nt * BN + bcol + n * 16 + l15;
        epi(z, grow, gcol, acc[m][n][r]);
      }
}

// ---------------------------------------------------------------------------
// QKV GEMM with FUSED qkv_post epilogue + FUSED Gram stats (R15 known-good).
// ---------------------------------------------------------------------------
__global__ __launch_bounds__(256, 3) void gemm_qkv(
    const bf16* __restrict__ A, const bf16* __restrict__ B,
    const float* __restrict__ bias, bf16* __restrict__ q2h,
    bf16* __restrict__ k2h, bf16* __restrict__ vth,
    float* __restrict__ Gq, float* __restrict__ Gk,
    float* __restrict__ Sq, float* __restrict__ Sk)
{
  constexpr int BM = 128, BN = 64, BK = 64;
  constexpr int AB = BM * BK * 2, BB = BN * BK * 2;
  constexpr int BUFB = AB + BB;
  constexpr int LPS = BUFB / 4096;
  __shared__ char smem[2 * BUFB];
  __shared__ float rowsum[2][BM];

  const int tid = threadIdx.x, lane = tid & 63, wv = tid >> 6;
  const int wr = wv >> 1, wc = wv & 1;
  const int NT = 36;
  const int wid = xcd_chunk(blockIdx.y * NT + blockIdx.x, NT * 32);
  const int mt = wid / NT, nt = wid % NT;
  const int sec = nt / 12, h = nt - sec * 12;
  const long abase = (long)mt * BM * 768;
  const long bbase = (long)nt * BN * 768;
  const int l15 = lane & 15, lhi = lane >> 4;
  const int sw = (lane & 7) << 4;

  auto stage_all = [&](int buf, int kt) {
    char* base = smem + buf * BUFB;
    stage_tile(A + abase + kt, 768, base, AB, tid);
    stage_tile(B + bbase + kt, 768, base + AB, BB, tid);
  };

  f32x4 acc[4][2];
#pragma unroll
  for (int m = 0; m < 4; ++m)
#pragma unroll
    for (int n = 0; n < 2; ++n) acc[m][n] = f32x4{0.f, 0.f, 0.f, 0.f};

  const int arow = wr * 64, bcol = wc * 32;

  stage_all(0, 0);
  int cur = 0;
  for (int t = 0; t < 12; ++t) {
    if (t + 1 < 12) { stage_all(cur ^ 1, (t + 1) * BK); waitvm<LPS>(); }
    else            { waitvm<0>(); }
    __builtin_amdgcn_s_barrier();
    asm volatile("" ::: "memory");

    const char* As = smem + cur * BUFB;
    const char* Bs = As + AB;
#pragma unroll
    for (int ks = 0; ks < 2; ++ks) {
      const int ko = (ks * 64 + lhi * 16) ^ sw;
      bf16x8 av[4], bv[2];
#pragma unroll
      for (int m = 0; m < 4; ++m)
        av[m] = *(const bf16x8*)(As + (arow + m * 16 + l15) * 128 + ko);
#pragma unroll
      for (int n = 0; n < 2; ++n)
        bv[n] = *(const bf16x8*)(Bs + (bcol + n * 16 + l15) * 128 + ko);
#pragma unroll
      for (int m = 0; m < 4; ++m)
#pragma unroll
        for (int n = 0; n < 2; ++n)
          acc[m][n] = __builtin_amdgcn_mfma_f32_16x16x32_bf16(av[m], bv[n], acc[m][n], 0, 0, 0);
    }
    asm volatile("s_waitcnt lgkmcnt(0)" ::: "memory");
    __builtin_amdgcn_s_barrier();
    asm volatile("" ::: "memory");
    cur ^= 1;
  }

  // ---- fused epilogue ----
  float val[4][2][4];
#pragma unroll
  for (int m = 0; m < 4; ++m)
#pragma unroll
    for (int n = 0; n < 2; ++n)
#pragma unroll
      for (int r = 0; r < 4; ++r)
        val[m][n][r] = acc[m][n][r] + bias[nt * 64 + bcol + n * 16 + l15];

  if (sec < 2) {
#pragma unroll
    for (int m = 0; m < 4; ++m)
#pragma unroll
      for (int r = 0; r < 4; ++r) {
        float p = val[m][0][r] * val[m][0][r] + val[m][1][r] * val[m][1][r];
        p += __shfl_xor(p, 1);
        p += __shfl_xor(p, 2);
        p += __shfl_xor(p, 4);
        p += __shfl_xor(p, 8);
        if (l15 == 0) rowsum[wc][arow + m * 16 + lhi * 4 + r] = p;
      }
    __syncthreads();

    bf16* dst = (sec == 0) ? q2h : k2h;
    float* G  = (sec == 0) ? Gq  : Gk;
    float* S  = (sec == 0) ? Sq  : Sk;
    const int bq = mt >> 3;
    const int z = bq * 12 + h;
    char* T0 = smem;            // [64 d][128B] swizzled, rows n' 0..63
    char* T1 = smem + 8192;     //                       rows n' 64..127
    float colsum[2] = {0.f, 0.f};
#pragma unroll
    for (int m = 0; m < 4; ++m)
#pragma unroll
      for (int r = 0; r < 4; ++r) {
        const int row = arow + m * 16 + lhi * 4 + r;     // 0..127
        const float inv = 1.0f / (rowsum[0][row] + rowsum[1][row]);
        const int grow = mt * BM + row;
        const int nn = grow & 1023;
        const long base = (((long)z) * 1024 + nn) * 64;
        char* Tt = (row & 64) ? T1 : T0;
        const int np = row & 63;
#pragma unroll
        for (int n = 0; n < 2; ++n) {
          const float v = val[m][n][r];
          const int d = bcol + n * 16 + l15;
          const bf16 q2b = (bf16)(v * v * inv);
          dst[base + d] = q2b;
          *(bf16*)(Tt + d * 128 + ((np * 2) ^ ((d & 7) << 4))) = q2b;
          colsum[n] += (float)q2b;
        }
      }
    // Sq/Sk: reduce over lhi (this wave's 64 rows), cross-wr via atomics.
#pragma unroll
    for (int n = 0; n < 2; ++n) {
      float s = colsum[n];
      s += __shfl_xor(s, 16);
      s += __shfl_xor(s, 32);
      if (lane < 16) atomicAdd(&S[z * 64 + bcol + n * 16 + l15], s);
    }
    __syncthreads();   // T fully written (all waves) before Gram reads

    // Gram: G[d][e] += sum_n q2[n][d]*q2[n][e]; wave wv owns 4 of 16 tiles.
#pragma unroll
    for (int gi = 0; gi < 4; ++gi) {
      const int g = wv * 4 + gi;
      const int dr = g >> 2, ec = g & 3;
      f32x4 ga = f32x4{0.f, 0.f, 0.f, 0.f};
#pragma unroll
      for (int ks = 0; ks < 4; ++ks) {
        const char* Tt = (ks & 2) ? T1 : T0;
        const int ko = ((ks & 1) * 64 + lhi * 16) ^ sw;
        const bf16x8 av = *(const bf16x8*)(Tt + (dr * 16 + l15) * 128 + ko);
        const bf16x8 bv = *(const bf16x8*)(Tt + (ec * 16 + l15) * 128 + ko);
        ga = __builtin_amdgcn_mfma_f32_16x16x32_bf16(av, bv, ga, 0, 0, 0);
      }
#pragma unroll
      for (int r = 0; r < 4; ++r)
        atomicAdd(&G[(long)z * 4096 + (dr * 16 + lhi * 4 + r) * 64 + ec * 16 + l15],
                  ga[r]);
    }
  } else {
    // v-section: transpose the 128(n) x 64(d) tile through LDS, then
    // coalesced bf16x8 stores to vth[(b*12+h)*64 + d][nn0 + c].
    bf16* T = (bf16*)smem;             // [64 d][pitch 144] (post-loop reuse)
#pragma unroll
    for (int m = 0; m < 4; ++m)
#pragma unroll
      for (int n = 0; n < 2; ++n)
#pragma unroll
        for (int r = 0; r < 4; ++r) {
          const int row = arow + m * 16 + lhi * 4 + r;   // 0..127 (n)
          const int col = bcol + n * 16 + l15;           // 0..63  (d)
          T[col * 144 + row] = (bf16)val[m][n][r];
        }
    __syncthreads();
    const int bq = mt >> 3, nn0 = (mt & 7) * 128;
    const long basez = ((long)(bq * 12 + h) * 64) * 1024;
#pragma unroll
    for (int it = 0; it < 4; ++it) {
      const int flat = it * 2048 + tid * 8;
      const int d = flat >> 7, c = flat & 127;
      const bf16x8 o = *(const bf16x8*)&T[d * 144 + c];
      *(bf16x8*)&vth[basez + (long)d * 1024 + nn0 + c] = o;
    }
  }
}

// ---------------------------------------------------------------------------
// Fused attention tail — R15 known-good form. Qs in LDS; 48KB -> 3 blocks/CU;
// counted vmcnt(4) store drain + one-iter-ahead wn/bn prefetch.
// ---------------------------------------------------------------------------
__global__ __launch_bounds__(256, 3) void attn_fused(
    const bf16* __restrict__ q2h, const bf16* __restrict__ k2h,
    const bf16* __restrict__ vth, const float* __restrict__ stats,
    const float* __restrict__ wn, const float* __restrict__ bn,
    float* __restrict__ attn_out, bf16* __restrict__ oh)
{
  __shared__ char smem[49152];
  char* Qs  = smem;                    //  8KB  64x64 bf16 (swizzled)
  char* Ks0 = smem + 8192;
  char* Ks1 = smem + 16384;
  char* Vs0 = smem + 24576;
  char* Vs1 = smem + 32768;
  char* Pall = smem + 40960;           //  8KB: 4 waves x [16][64] bf16 (swz)

  const int tid = threadIdx.x, lane = tid & 63, wv = tid >> 6;
  const int wid = xcd_chunk(blockIdx.x, 768);
  const int b = wid & 3;               // fastest: wn/bn strip sharing
  const int mt = (wid >> 2) & 15;
  const int h = wid >> 6;
  const int zq = b * 12 + h;
  const float mu = stats[2 * b], rs = stats[2 * b + 1];
  const int l15 = lane & 15, lhi = lane >> 4;
  const int sw = (lane & 7) << 4;
  char* Ps = Pall + wv * 2048;         // wave-private [16 rows][128B]

  const long zoff = (long)zq * 65536;

  auto load_wb = [&](int nt, f32x4* wreg, f32x4* breg) {
#pragma unroll
    for (int rr = 0; rr < 4; ++rr) {
      const long grow = (long)mt * 64 + wv * 16 + rr * 4 + lhi;
      const long gcol = (long)nt * 64 + l15 * 4;
      wreg[rr] = *(const f32x4*)&wn[((long)h * 1024 + grow) * 1024 + gcol];
      breg[rr] = *(const f32x4*)&bn[((long)h * 1024 + grow) * 1024 + gcol];
    }
  };

  f32x4 wcur[4], bcur[4];
  load_wb(0, wcur, bcur);
  stage_tile(q2h + zoff + (long)mt * 4096, 64, Qs, 8192, tid);
  stage_tile(k2h + zoff, 64, Ks0, 8192, tid);
  stage_tile(vth + zoff, 1024, Vs0, 8192, tid);
  __syncthreads();

  f32x4 oacc[4];
#pragma unroll
  for (int n = 0; n < 4; ++n) oacc[n] = f32x4{0.f, 0.f, 0.f, 0.f};

  for (int nt = 0; nt < 16; ++nt) {
    const int cur = nt & 1;
    char* Kc = cur ? Ks1 : Ks0;
    char* Vc = cur ? Vs1 : Vs0;
    char* Kn = cur ? Ks0 : Ks1;
    char* Vn = cur ? Vs0 : Vs1;

    // next-iter prefetch: wn/bn to regs, then K/V DMA (counted at iter end).
    f32x4 wnx[4], bnx[4];
    if (nt + 1 < 16) {
      load_wb(nt + 1, wnx, bnx);
      stage_tile(k2h + zoff + (long)(nt + 1) * 4096, 64, Kn, 8192, tid);
      stage_tile(vth + zoff + (nt + 1) * 64, 1024, Vn, 8192, tid);
    }

    // ---- QK^T: wave computes its 16 rows x all 64 cols ----
    f32x4 acc[4];
#pragma unroll
    for (int n = 0; n < 4; ++n) acc[n] = f32x4{0.f, 0.f, 0.f, 0.f};
    __builtin_amdgcn_s_setprio(1);
#pragma unroll
    for (int ks = 0; ks < 2; ++ks) {
      const int ko = (ks * 64 + lhi * 16) ^ sw;
      const bf16x8 av = *(const bf16x8*)(Qs + (wv * 16 + l15) * 128 + ko);
#pragma unroll
      for (int n = 0; n < 4; ++n) {
        const bf16x8 bv = *(const bf16x8*)(Kc + (n * 16 + l15) * 128 + ko);
        acc[n] = __builtin_amdgcn_mfma_f32_16x16x32_bf16(av, bv, acc[n], 0, 0, 0);
      }
    }
    __builtin_amdgcn_s_setprio(0);
    // s_ln = (s-mu)*rs -> bf16, into wave-private Ps (swizzled).
#pragma unroll
    for (int n = 0; n < 4; ++n)
#pragma unroll
      for (int r = 0; r < 4; ++r) {
        const int row = lhi * 4 + r;                 // local row 0..15
        const int cb = (n * 32 + l15 * 2) ^ ((row & 7) << 4);
        *(bf16*)(Ps + row * 128 + cb) = (bf16)((acc[n][r] - mu) * rs);
      }
    wave_lds_fence();  // cross-lane RAW within wave: QK^T writes -> LN reads

    // ---- LN: r = s_ln*w + b -> attn_out f32x4 (coalesced) + Ps in-place ----
#pragma unroll
    for (int rr = 0; rr < 4; ++rr) {
      const int row = rr * 4 + lhi;                  // local row 0..15
      const int cb = (l15 * 8) ^ ((row & 7) << 4);
      const bf16x4 s4 = *(const bf16x4*)(Ps + row * 128 + cb);
      const long grow = (long)mt * 64 + wv * 16 + row;
      const long gcol = (long)nt * 64 + l15 * 4;
      f32x4 r4;
      bf16x4 h4;
#pragma unroll
      for (int e = 0; e < 4; ++e) {
        const float r = (float)s4[e] * wcur[rr][e] + bcur[rr][e];
        r4[e] = r;
        h4[e] = (bf16)r;
      }
      *(f32x4*)&attn_out[((long)zq * 1024 + grow) * 1024 + gcol] = r4;
      *(bf16x4*)(Ps + row * 128 + cb) = h4;
    }
    wave_lds_fence();  // cross-lane RAW within wave: LN write-back -> PV reads

    // ---- PV: o[row, d] += sum_j P[row,j] vT[d,j] ----
    __builtin_amdgcn_s_setprio(1);
#pragma unroll
    for (int ks = 0; ks < 2; ++ks) {
      const int ko = (ks * 64 + lhi * 16) ^ sw;
      const bf16x8 av = *(const bf16x8*)(Ps + l15 * 128 + ko);
#pragma unroll
      for (int n = 0; n < 4; ++n) {
        const bf16x8 bv = *(const bf16x8*)(Vc + (n * 16 + l15) * 128 + ko);
        oacc[n] = __builtin_amdgcn_mfma_f32_16x16x32_bf16(av, bv, oacc[n], 0, 0, 0);
      }
    }
    __builtin_amdgcn_s_setprio(0);
    // counted drain: the 4 newest VMEM ops (attn stores) may stay in flight;
    // everything older (K/V DMA + wb loads) is forced complete.
    waitvm<4>();
    __builtin_amdgcn_s_barrier();
    asm volatile("" ::: "memory");

    if (nt + 1 < 16) {
#pragma unroll
      for (int rr = 0; rr < 4; ++rr) { wcur[rr] = wnx[rr]; bcur[rr] = bnx[rr]; }
    }
  }

  // ---- epilogue: o -> (B,N,C) bf16 ----
#pragma unroll
  for (int n = 0; n < 4; ++n)
#pragma unroll
    for (int r = 0; r < 4; ++r) {
      const int row = mt * 64 + wv * 16 + lhi * 4 + r;
      const int col = n * 16 + l15;
      oh[((long)(b * 1024 + row)) * 768 + h * 64 + col] = (bf16)oacc[n][r];
    }
}

// ---------------------------------------------------------------------------
// prep: all four weight casts + LN0 in ONE launch (block-range split).
// ---------------------------------------------------------------------------
__global__ __launch_bounds__(256) void prep(
    const float* __restrict__ qkvw, const float* __restrict__ projw,
    const float* __restrict__ fc1w, const float* __restrict__ fc2w,
    bf16* __restrict__ dq, bf16* __restrict__ dp,
    bf16* __restrict__ d1, bf16* __restrict__ d2,
    const float* __restrict__ x, const float* __restrict__ w,
    const float* __restrict__ bb, bf16* __restrict__ outh)
{
  __shared__ float red[256];
  const int bid = blockIdx.x, tid = threadIdx.x;
  if (bid < 6912) {
    const int i = bid * 256 + tid;     // n4 index over 1769472
    const float* s; bf16* d; int off;
    if (i < 442368)       { s = qkvw; d = dq; off = i; }
    else if (i < 589824)  { s = projw; d = dp; off = i - 442368; }
    else if (i < 1179648) { s = fc1w; d = d1; off = i - 589824; }
    else                  { s = fc2w; d = d2; off = i - 1179648; }
    const f32x4 v = *(const f32x4*)&s[(long)off * 4];
    bf16x4 o;
#pragma unroll
    for (int j = 0; j < 4; ++j) o[j] = (bf16)v[j];
    *(bf16x4*)&d[(long)off * 4] = o;
  } else {
    const int row = bid - 6912;
    const float* p = x + (long)row * 768;
    const float v0 = p[tid], v1 = p[tid + 256], v2 = p[tid + 512];
    red[tid] = v0 + v1 + v2;
    __syncthreads();
    for (int st = 128; st > 0; st >>= 1) { if (tid < st) red[tid] += red[tid + st]; __syncthreads(); }
    const float mu = red[0] * (1.0f / 768.0f);
    __syncthreads();
    const float d0 = v0 - mu, d1v = v1 - mu, d2v = v2 - mu;
    red[tid] = d0 * d0 + d1v * d1v + d2v * d2v;
    __syncthreads();
    for (int st = 128; st > 0; st >>= 1) { if (tid < st) red[tid] += red[tid + st]; __syncthreads(); }
    const float rs = rsqrtf(red[0] * (1.0f / 768.0f) + 1e-5f);
    const float dv[3] = {d0, d1v, d2v};
#pragma unroll
    for (int k = 0; k < 3; ++k) {
      const int c = tid + k * 256;
      outh[(long)row * 768 + c] = (bf16)(dv[k] * rs * w[c] + bb[c]);
    }
  }
}

// LayerNorm over rows of 768; writes bf16 (+ optional f32). (LN1)
__global__ __launch_bounds__(256) void ln_row(
    const float* __restrict__ in, const float* __restrict__ w,
    const float* __restrict__ b, bf16* __restrict__ outh,
    float* __restrict__ outf)
{
  __shared__ float red[256];
  const int row = blockIdx.x, tid = threadIdx.x;
  const float* p = in + (long)row * 768;
  const float v0 = p[tid], v1 = p[tid + 256], v2 = p[tid + 512];
  red[tid] = v0 + v1 + v2;
  __syncthreads();
  for (int st = 128; st > 0; st >>= 1) { if (tid < st) red[tid] += red[tid + st]; __syncthreads(); }
  const float mu = red[0] * (1.0f / 768.0f);
  __syncthreads();
  const float d0 = v0 - mu, d1 = v1 - mu, d2 = v2 - mu;
  red[tid] = d0 * d0 + d1 * d1 + d2 * d2;
  __syncthreads();
  for (int st = 128; st > 0; st >>= 1) { if (tid < st) red[tid] += red[tid + st]; __syncthreads(); }
  const float rs = rsqrtf(red[0] * (1.0f / 768.0f) + 1e-5f);
  const float dv[3] = {d0, d1, d2};
#pragma unroll
  for (int k = 0; k < 3; ++k) {
    const int c = tid + k * 256;
    const float h = dv[k] * rs * w[c] + b[c];
    outh[(long)row * 768 + c] = (bf16)h;
    if (outf) outf[(long)row * 768 + c] = h;
  }
}

// Per-batch mean / rstd of the attn tensor from Gram partials.
__global__ __launch_bounds__(256) void stats_final(
    const float* __restrict__ Gq, const float* __restrict__ Gk,
    const float* __restrict__ Sq, const float* __restrict__ Sk,
    float* __restrict__ stats)
{
  __shared__ double red[256];
  const int b = blockIdx.x, tid = threadIdx.x;
  double s2 = 0.0, s1 = 0.0;
  for (int h = 0; h < 12; ++h) {
    const float* gq = Gq + ((long)(b * 12 + h)) * 4096;
    const float* gk = Gk + ((long)(b * 12 + h)) * 4096;
    for (int i = tid; i < 4096; i += 256) s2 += (double)gq[i] * (double)gk[i];
    const float* sqp = Sq + (b * 12 + h) * 64;
    const float* skp = Sk + (b * 12 + h) * 64;
    for (int i = tid; i < 64; i += 256) s1 += (double)sqp[i] * (double)skp[i];
  }
  red[tid] = s2; __syncthreads();
  for (int st = 128; st > 0; st >>= 1) { if (tid < st) red[tid] += red[tid + st]; __syncthreads(); }
  const double S2 = red[0]; __syncthreads();
  red[tid] = s1; __syncthreads();
  for (int st = 128; st > 0; st >>= 1) { if (tid < st) red[tid] += red[tid + st]; __syncthreads(); }
  if (tid == 0) {
    const double S1 = red[0];
    const double cnt = 12.0 * 1024.0 * 1024.0;
    const double mean = S1 / cnt;
    const double var = S2 / cnt - mean * mean;
    stats[2 * b] = (float)mean;
    stats[2 * b + 1] = (float)(1.0 / sqrt(var + 1e-5));
  }
}

// ---------------------------------------------------------------------------
extern "C" void kernel_launch(void* const* d_in, const int* in_sizes, int n_in,
                              void* d_out, int out_size, void* d_ws, size_t ws_size,
                              hipStream_t stream)
{
  const float* x      = (const float*)d_in[0];
  const float* ln0_w  = (const float*)d_in[1];
  const float* ln0_b  = (const float*)d_in[2];
  const float* qkv_w  = (const float*)d_in[3];
  const float* qkv_b  = (const float*)d_in[4];
  const float* proj_w = (const float*)d_in[5];
  const float* proj_b = (const float*)d_in[6];
  const float* attn_w = (const float*)d_in[7];
  const float* attn_b = (const float*)d_in[8];
  const float* ln1_w  = (const float*)d_in[9];
  const float* ln1_b  = (const float*)d_in[10];
  const float* fc1_w  = (const float*)d_in[11];
  const float* fc1_b  = (const float*)d_in[12];
  const float* fc2_w  = (const float*)d_in[13];
  const float* fc2_b  = (const float*)d_in[14];

  float* out_src  = (float*)d_out;
  float* out_attn = out_src + 4L * 1024 * 768;       // 3145728

  char* p = (char*)d_ws;
  auto take = [&](long bytes) -> char* {
    char* r = p;
    p += (bytes + 255) & ~255L;
    return r;
  };
  bf16* qkvw_h = (bf16*)take(3538944);
  bf16* projw_h = (bf16*)take(1179648);
  bf16* fc1w_h = (bf16*)take(4718592);
  bf16* fc2w_h = (bf16*)take(4718592);
  char* regB = take(12582912);                 // hh, later src_f32
  bf16* hh = (bf16*)regB;
  float* src = (float*)regB;
  char* regC = take(37748736);                 // gelu acts + ln1f
  bf16* gact = (bf16*)regC;                    // [0, 25165824) bf16 4096x3072
  float* ln1f = (float*)(regC + 25165824);     // [25165824, 37748736) f32
  bf16* q2h = (bf16*)take(6291456);
  bf16* k2h = (bf16*)take(6291456);
  bf16* vth = (bf16*)take(6291456);
  bf16* oh  = (bf16*)take(6291456);
  bf16* h1v = (bf16*)take(6291456);
  float* Gq = (float*)take(786432);
  float* Gk = (float*)take(786432);
  float* Sq = (float*)take(12288);
  float* Sk = (float*)take(12288);
  float* stats = (float*)take(256);

  const dim3 blk(256);

  (void)hipMemsetAsync((void*)Gq, 0, 786432 * 2 + 12288 * 2 + 256, stream);

  prep<<<dim3(11008), blk, 0, stream>>>(
      qkv_w, proj_w, fc1_w, fc2_w, qkvw_h, projw_h, fc1w_h, fc2w_h,
      x, ln0_w, ln0_b, hh);

  gemm_qkv<<<dim3(36, 32), blk, 0, stream>>>(
      hh, qkvw_h, qkv_b, q2h, k2h, vth, Gq, Gk, Sq, Sk);

  stats_final<<<dim3(4), blk, 0, stream>>>(Gq, Gk, Sq, Sk, stats);

  attn_fused<<<dim3(768), blk, 0, stream>>>(
      q2h, k2h, vth, stats, attn_w, attn_b, out_attn, oh);

  // proj: 64x64 tiles -> grid 768 blocks = exact fill at 4 blocks/CU.
  gemm_k<64, 64, 2, 2, 2, 4, EpiProj><<<dim3(12, 64, 1), blk, 0, stream>>>(
      oh, 0, projw_h, 0, 768, 768, 768, EpiProj{proj_b, x, src});

  ln_row<<<dim3(4096), blk, 0, stream>>>(src, ln1_w, ln1_b, h1v, ln1f);

  gemm_k<128, 64, 2, 4, 2, 3, EpiGelu><<<dim3(48, 32, 1), blk, 0, stream>>>(
      h1v, 0, fc1w_h, 0, 768, 768, 768, EpiGelu{fc1_b, gact});

  // fc2: 64x64 tiles -> grid 768 blocks = exact fill (was 384 = half idle).
  gemm_k<64, 64, 2, 2, 2, 4, EpiOut><<<dim3(12, 64, 1), blk, 0, stream>>>(
      gact, 0, fc2w_h, 0, 3072, 3072, 3072, EpiOut{fc2_b, ln1f, out_src});
}